// Round 9
// baseline (16.569 us; speedup 1.0000x reference)
//
#include <hip/hip_runtime.h>

#define DIM 1024
#define HEADS 16
#define BATCH 2
#define SEQ 2048
#define NTERM 32           // Taylor coefficients T_0..T_31

// ws float layout:
// 4 partial sets over j-quarters; each set: {qa,qb,ka,va,vb}[1024] (5120 floats)
#define WS_P    0
#define WS_U    20480      // u[1024] = wo @ wf
#define WS_T    24576      // T[b][q][n]: prefix sums of x^n/n!, 2*2048*32 floats

// grid 512 (2 blocks/CU, balanced):
//   [0,384)   QKV quarter-partials: m = bid/128; r = bid%128; slice=(r>>2), jq=r&3
//   [384,448) wo@wf rows, 16 per block
//   [448,512) prefix-scan blocks, one per (batch, n)
__global__ __launch_bounds__(256) void k1_weights(
        const float* __restrict__ x,
        const float* __restrict__ w_in, const float* __restrict__ b_in,
        const float* __restrict__ wq,   const float* __restrict__ wk,
        const float* __restrict__ wv,   const float* __restrict__ wo,
        const float* __restrict__ wf,   float* __restrict__ ws) {
    const int bid = blockIdx.x;
    const int tid = threadIdx.x;
    if (bid < 384) {
        const int m  = bid >> 7;               // 0=wq 1=wk 2=wv
        const int r  = bid & 127;
        const int jq = r & 3;                  // j-quarter (256 rows)
        const int d0 = (r >> 2) * 32;          // 32-wide d-slice
        const int dl = tid & 7;                // float4 col within slice
        const int jg = tid >> 3;               // 32 j-groups of 8 rows
        const int j0 = jq * 256 + jg * 8;
        const float* Wm = (m == 0) ? wq : (m == 1) ? wk : wv;
        float4 a1 = {0, 0, 0, 0}, a2 = {0, 0, 0, 0};
        #pragma unroll
        for (int i = 0; i < 8; ++i) {
            const int j = j0 + i;
            const float4 v = *reinterpret_cast<const float4*>(Wm + j * DIM + d0 + 4 * dl);
            const float wi = w_in[j];
            a1.x += wi * v.x; a1.y += wi * v.y; a1.z += wi * v.z; a1.w += wi * v.w;
            if (m != 1) {
                const float bi = b_in[j];
                a2.x += bi * v.x; a2.y += bi * v.y; a2.z += bi * v.z; a2.w += bi * v.w;
            }
        }
        __shared__ float sh1[32][33], sh2[32][33];
        sh1[jg][4 * dl + 0] = a1.x;
        sh1[jg][4 * dl + 1] = a1.y;
        sh1[jg][4 * dl + 2] = a1.z;
        sh1[jg][4 * dl + 3] = a1.w;
        if (m != 1) {
            sh2[jg][4 * dl + 0] = a2.x;
            sh2[jg][4 * dl + 1] = a2.y;
            sh2[jg][4 * dl + 2] = a2.z;
            sh2[jg][4 * dl + 3] = a2.w;
        }
        __syncthreads();
        if (tid < 32) {
            float f1 = 0.f, f2 = 0.f;
            #pragma unroll
            for (int g = 0; g < 32; ++g) {
                f1 += sh1[g][tid];
                if (m != 1) f2 += sh2[g][tid];
            }
            const int base = WS_P + jq * 5120;
            const int d = d0 + tid;
            if (m == 0)      { ws[base + d] = f1; ws[base + 1024 + d] = f2; }
            else if (m == 1) { ws[base + 2048 + d] = f1; }
            else             { ws[base + 3072 + d] = f1; ws[base + 4096 + d] = f2; }
        }
    } else if (bid < 448) {
        // u[row] = wo[row,:] . wf ; 16 rows per block, 4 per wave
        const int wave = tid >> 6, lane = tid & 63;
        const int rb = bid - 384;
        #pragma unroll
        for (int rr = 0; rr < 4; ++rr) {
            const int row = rb * 16 + wave * 4 + rr;
            const float4* wo4 = reinterpret_cast<const float4*>(wo + row * DIM);
            const float4* wf4 = reinterpret_cast<const float4*>(wf);
            float s = 0.f;
            #pragma unroll
            for (int e = lane; e < 256; e += 64) {
                const float4 a = wo4[e], b = wf4[e];
                s += a.x * b.x + a.y * b.y + a.z * b.z + a.w * b.w;
            }
            #pragma unroll
            for (int off = 32; off; off >>= 1) s += __shfl_down(s, off);
            if (lane == 0) ws[WS_U + row] = s;
        }
    } else {
        // prefix scan of x^n/n! for one (b, n); 256 threads x 8 elements
        // writes transposed: T[b][q][n]
        const int sb = bid - 448;
        const int b = sb >> 5, n = sb & 31;
        const float* xb = x + b * SEQ;
        const float4 xa = ((const float4*)xb)[2 * tid];
        const float4 xc = ((const float4*)xb)[2 * tid + 1];
        float xv[8] = {xa.x, xa.y, xa.z, xa.w, xc.x, xc.y, xc.z, xc.w};
        float pw[8];
        #pragma unroll
        for (int e = 0; e < 8; ++e) pw[e] = 1.f;
        float f = 1.f;
        for (int i = 1; i <= n; ++i) {          // runtime n <= 31
            f *= (float)i;
            #pragma unroll
            for (int e = 0; e < 8; ++e) pw[e] *= xv[e];
        }
        const float rf = 1.0f / f;
        float p[8];
        float s = 0.f;
        #pragma unroll
        for (int e = 0; e < 8; ++e) { s += pw[e] * rf; p[e] = s; }
        const int lane = tid & 63, wv = tid >> 6;
        float incl = s;
        #pragma unroll
        for (int off = 1; off < 64; off <<= 1) {
            const float v = __shfl_up(incl, off);
            if (lane >= off) incl += v;
        }
        __shared__ float wsum[4];
        if (lane == 63) wsum[wv] = incl;
        __syncthreads();
        float base = incl - s;                  // exclusive within wave
        if (wv > 0) base += wsum[0];
        if (wv > 1) base += wsum[1];
        if (wv > 2) base += wsum[2];
        #pragma unroll
        for (int e = 0; e < 8; ++e) {
            const int q = tid * 8 + e;
            ws[WS_T + (b * SEQ + q) * NTERM + n] = base + p[e];
        }
    }
}

// 256 blocks x 256 threads. Each block recomputes the 49 head scalars from the
// L2-hot partial vectors, then Horner-evaluates num/den per (b,q,h):
// den = sum_n alpha^n T_n(q),  num = sum_n alpha^n n T_n(q) (as dnum below)
__global__ __launch_bounds__(256) void k2_eval(
        const float* __restrict__ x,  const float* __restrict__ bo,
        const float* __restrict__ wf, const float* __restrict__ bf,
        const float* __restrict__ ws, float* __restrict__ out) {
    const int tid = threadIdx.x;
    const int wave = tid >> 6, lane = tid & 63;

    __shared__ float sA[HEADS], sC[HEADS], sG[HEADS];
    __shared__ float c0p[4];

    #pragma unroll
    for (int hh = 0; hh < 4; ++hh) {
        const int h = wave * 4 + hh;
        const int d = h * 64 + lane;
        float qa = 0.f, qb = 0.f, ka = 0.f, va = 0.f;
        #pragma unroll
        for (int jq = 0; jq < 4; ++jq) {
            const float* P = ws + WS_P + jq * 5120 + d;
            qa += P[0];
            qb += P[1024];
            ka += P[2048];
            va += P[3072];
        }
        const float u = ws[WS_U + d];
        float pA = qa * ka, pC = qb * ka, pG = va * u;
        #pragma unroll
        for (int off = 32; off; off >>= 1) {
            pA += __shfl_down(pA, off);
            pC += __shfl_down(pC, off);
            pG += __shfl_down(pG, off);
        }
        if (lane == 0) { sA[h] = pA; sC[h] = pC; sG[h] = pG; }
    }
    {
        float s = 0.f;
        #pragma unroll
        for (int t = 0; t < 4; ++t) {
            const int d = wave * 256 + t * 64 + lane;
            float vb = 0.f;
            #pragma unroll
            for (int jq = 0; jq < 4; ++jq) vb += ws[WS_P + jq * 5120 + 4096 + d];
            s += vb * ws[WS_U + d] + bo[d] * wf[d];
        }
        #pragma unroll
        for (int off = 32; off; off >>= 1) s += __shfl_down(s, off);
        if (lane == 0) c0p[wave] = s;
    }
    __syncthreads();
    const float c0 = c0p[0] + c0p[1] + c0p[2] + c0p[3] + bf[0];

    const int g = blockIdx.x * 256 + tid;    // 65536 = 2*2048*16
    const int h = g & 15;
    const int q = (g >> 4) & (SEQ - 1);
    const int b = g >> 15;
    const float xq = x[b * SEQ + q];
    const float al = 0.125f * (sA[h] * xq + sC[h]);
    const float4* T4 = reinterpret_cast<const float4*>(ws + WS_T + (b * SEQ + q) * NTERM);
    float tr[NTERM];
    #pragma unroll
    for (int i = 0; i < 8; ++i) {
        const float4 v = T4[i];
        tr[4 * i + 0] = v.x;
        tr[4 * i + 1] = v.y;
        tr[4 * i + 2] = v.z;
        tr[4 * i + 3] = v.w;
    }
    float den = tr[31];
    float num = 31.f * tr[31];
    #pragma unroll
    for (int j = 30; j >= 1; --j) {
        den = den * al + tr[j];
        num = num * al + (float)j * tr[j];
    }
    den = den * al + tr[0];                  // T_0 = q+1
    float r = sG[h] * (num / den);
    r += __shfl_down(r, 8);
    r += __shfl_down(r, 4);
    r += __shfl_down(r, 2);
    r += __shfl_down(r, 1);
    if (h == 0) out[b * SEQ + q] = c0 + r;
}

extern "C" void kernel_launch(void* const* d_in, const int* in_sizes, int n_in,
                              void* d_out, int out_size, void* d_ws, size_t ws_size,
                              hipStream_t stream) {
    const float* x    = (const float*)d_in[0];
    const float* w_in = (const float*)d_in[1];
    const float* b_in = (const float*)d_in[2];
    const float* wq   = (const float*)d_in[3];
    const float* wk   = (const float*)d_in[4];
    const float* wv   = (const float*)d_in[5];
    const float* wo   = (const float*)d_in[6];
    const float* bo   = (const float*)d_in[7];
    const float* wf   = (const float*)d_in[8];
    const float* bf   = (const float*)d_in[9];
    float* out = (float*)d_out;
    float* ws  = (float*)d_ws;

    k1_weights<<<512, 256, 0, stream>>>(x, w_in, b_in, wq, wk, wv, wo, wf, ws);
    k2_eval<<<256, 256, 0, stream>>>(x, bo, wf, bf, ws, out);
}

// Round 10
// 16.042 us; speedup vs baseline: 1.0328x; 1.0328x over previous
//
#include <hip/hip_runtime.h>

#define DIM 1024
#define HEADS 16
#define BATCH 2
#define SEQ 2048
#define NTERM 32           // Taylor coefficients T_0..T_31

// ws float layout:
// 4 partial sets over j-quarters; each set: {qa,qb,ka,va,vb}[1024] (5120 floats)
#define WS_P    0
#define WS_U    20480      // u[1024] = wo @ wf
#define WS_T    24576      // T[b][n][q]: prefix sums of x^n/n!, 2*32*2048 floats

// grid 512 (2 blocks/CU, balanced ~32-64KB HBM per block):
//   [0,384)   QKV quarter-partials: m = bid/128; r = bid%128; slice=(r>>2), jq=r&3
//   [384,448) wo@wf rows, 16 per block
//   [448,512) prefix-scan blocks, one per (batch, n)
__global__ __launch_bounds__(256) void k1_weights(
        const float* __restrict__ x,
        const float* __restrict__ w_in, const float* __restrict__ b_in,
        const float* __restrict__ wq,   const float* __restrict__ wk,
        const float* __restrict__ wv,   const float* __restrict__ wo,
        const float* __restrict__ wf,   float* __restrict__ ws) {
    const int bid = blockIdx.x;
    const int tid = threadIdx.x;
    if (bid < 384) {
        const int m  = bid >> 7;               // 0=wq 1=wk 2=wv
        const int r  = bid & 127;
        const int jq = r & 3;                  // j-quarter (256 rows)
        const int d0 = (r >> 2) * 32;          // 32-wide d-slice
        const int dl = tid & 7;                // float4 col within slice
        const int jg = tid >> 3;               // 32 j-groups of 8 rows
        const int j0 = jq * 256 + jg * 8;
        const float* Wm = (m == 0) ? wq : (m == 1) ? wk : wv;
        float4 a1 = {0, 0, 0, 0}, a2 = {0, 0, 0, 0};
        #pragma unroll
        for (int i = 0; i < 8; ++i) {
            const int j = j0 + i;
            const float4 v = *reinterpret_cast<const float4*>(Wm + j * DIM + d0 + 4 * dl);
            const float wi = w_in[j];
            a1.x += wi * v.x; a1.y += wi * v.y; a1.z += wi * v.z; a1.w += wi * v.w;
            if (m != 1) {
                const float bi = b_in[j];
                a2.x += bi * v.x; a2.y += bi * v.y; a2.z += bi * v.z; a2.w += bi * v.w;
            }
        }
        __shared__ float sh1[32][33], sh2[32][33];
        sh1[jg][4 * dl + 0] = a1.x;
        sh1[jg][4 * dl + 1] = a1.y;
        sh1[jg][4 * dl + 2] = a1.z;
        sh1[jg][4 * dl + 3] = a1.w;
        if (m != 1) {
            sh2[jg][4 * dl + 0] = a2.x;
            sh2[jg][4 * dl + 1] = a2.y;
            sh2[jg][4 * dl + 2] = a2.z;
            sh2[jg][4 * dl + 3] = a2.w;
        }
        __syncthreads();
        if (tid < 32) {
            float f1 = 0.f, f2 = 0.f;
            #pragma unroll
            for (int g = 0; g < 32; ++g) {
                f1 += sh1[g][tid];
                if (m != 1) f2 += sh2[g][tid];
            }
            const int base = WS_P + jq * 5120;
            const int d = d0 + tid;
            if (m == 0)      { ws[base + d] = f1; ws[base + 1024 + d] = f2; }
            else if (m == 1) { ws[base + 2048 + d] = f1; }
            else             { ws[base + 3072 + d] = f1; ws[base + 4096 + d] = f2; }
        }
    } else if (bid < 448) {
        // u[row] = wo[row,:] . wf ; 16 rows per block, 4 per wave
        const int wave = tid >> 6, lane = tid & 63;
        const int rb = bid - 384;
        #pragma unroll
        for (int rr = 0; rr < 4; ++rr) {
            const int row = rb * 16 + wave * 4 + rr;
            const float4* wo4 = reinterpret_cast<const float4*>(wo + row * DIM);
            const float4* wf4 = reinterpret_cast<const float4*>(wf);
            float s = 0.f;
            #pragma unroll
            for (int e = lane; e < 256; e += 64) {
                const float4 a = wo4[e], b = wf4[e];
                s += a.x * b.x + a.y * b.y + a.z * b.z + a.w * b.w;
            }
            #pragma unroll
            for (int off = 32; off; off >>= 1) s += __shfl_down(s, off);
            if (lane == 0) ws[WS_U + row] = s;
        }
    } else {
        // prefix scan of x^n/n! for one (b, n); 256 threads x 8 elements
        // contiguous float4 writes into T[b][n][q]
        const int sb = bid - 448;
        const int b = sb >> 5, n = sb & 31;
        const float* xb = x + b * SEQ;
        const float4 xa = ((const float4*)xb)[2 * tid];
        const float4 xc = ((const float4*)xb)[2 * tid + 1];
        float xv[8] = {xa.x, xa.y, xa.z, xa.w, xc.x, xc.y, xc.z, xc.w};
        float pw[8];
        #pragma unroll
        for (int e = 0; e < 8; ++e) pw[e] = 1.f;
        float f = 1.f;
        for (int i = 1; i <= n; ++i) {          // runtime n <= 31
            f *= (float)i;
            #pragma unroll
            for (int e = 0; e < 8; ++e) pw[e] *= xv[e];
        }
        const float rf = 1.0f / f;
        float p[8];
        float s = 0.f;
        #pragma unroll
        for (int e = 0; e < 8; ++e) { s += pw[e] * rf; p[e] = s; }
        const int lane = tid & 63, wv = tid >> 6;
        float incl = s;
        #pragma unroll
        for (int off = 1; off < 64; off <<= 1) {
            const float v = __shfl_up(incl, off);
            if (lane >= off) incl += v;
        }
        __shared__ float wsum[4];
        if (lane == 63) wsum[wv] = incl;
        __syncthreads();
        float base = incl - s;                  // exclusive within wave
        if (wv > 0) base += wsum[0];
        if (wv > 1) base += wsum[1];
        if (wv > 2) base += wsum[2];
        float* Trow = ws + WS_T + (b * NTERM + n) * SEQ;
        ((float4*)Trow)[2 * tid]     = make_float4(base + p[0], base + p[1], base + p[2], base + p[3]);
        ((float4*)Trow)[2 * tid + 1] = make_float4(base + p[4], base + p[5], base + p[6], base + p[7]);
    }
}

// 256 blocks x 256 threads. Each block recomputes the 49 head scalars from the
// L2-hot partial vectors, then Horner-evaluates num/den per (b,q,h):
// den = sum_n alpha^n T_n(q),  num = sum_n alpha^n n T_n(q)
__global__ __launch_bounds__(256) void k2_eval(
        const float* __restrict__ x,  const float* __restrict__ bo,
        const float* __restrict__ wf, const float* __restrict__ bf,
        const float* __restrict__ ws, float* __restrict__ out) {
    const int tid = threadIdx.x;
    const int wave = tid >> 6, lane = tid & 63;

    // ---- issue eval loads first: latency hides under the scalar recompute ----
    const int g = blockIdx.x * 256 + tid;    // 65536 = 2*2048*16
    const int h = g & 15;
    const int q = (g >> 4) & (SEQ - 1);
    const int b = g >> 15;
    const float xq = x[b * SEQ + q];
    const float* T = ws + WS_T + b * NTERM * SEQ + q;
    float tr[NTERM];
    #pragma unroll
    for (int n = 0; n < NTERM; ++n) tr[n] = T[n * SEQ];

    // ---- per-head scalars from the 4 partial sets ----
    __shared__ float sA[HEADS], sC[HEADS], sG[HEADS];
    __shared__ float c0p[4];

    #pragma unroll
    for (int hh = 0; hh < 4; ++hh) {
        const int hd = wave * 4 + hh;
        const int d = hd * 64 + lane;
        float qa = 0.f, qb = 0.f, ka = 0.f, va = 0.f;
        #pragma unroll
        for (int jq = 0; jq < 4; ++jq) {
            const float* P = ws + WS_P + jq * 5120 + d;
            qa += P[0];
            qb += P[1024];
            ka += P[2048];
            va += P[3072];
        }
        const float u = ws[WS_U + d];
        float pA = qa * ka, pC = qb * ka, pG = va * u;
        #pragma unroll
        for (int off = 32; off; off >>= 1) {
            pA += __shfl_down(pA, off);
            pC += __shfl_down(pC, off);
            pG += __shfl_down(pG, off);
        }
        if (lane == 0) { sA[hd] = pA; sC[hd] = pC; sG[hd] = pG; }
    }
    {
        float s = 0.f;
        #pragma unroll
        for (int t = 0; t < 4; ++t) {
            const int d = wave * 256 + t * 64 + lane;
            float vb = 0.f;
            #pragma unroll
            for (int jq = 0; jq < 4; ++jq) vb += ws[WS_P + jq * 5120 + 4096 + d];
            s += vb * ws[WS_U + d] + bo[d] * wf[d];
        }
        #pragma unroll
        for (int off = 32; off; off >>= 1) s += __shfl_down(s, off);
        if (lane == 0) c0p[wave] = s;
    }
    __syncthreads();
    const float c0 = c0p[0] + c0p[1] + c0p[2] + c0p[3] + bf[0];

    // ---- Horner eval ----
    const float al = 0.125f * (sA[h] * xq + sC[h]);
    float den = tr[31];
    float num = 31.f * tr[31];
    #pragma unroll
    for (int j = 30; j >= 1; --j) {
        den = den * al + tr[j];
        num = num * al + (float)j * tr[j];
    }
    den = den * al + tr[0];                  // T_0 = q+1
    float r = sG[h] * (num / den);
    r += __shfl_down(r, 8);
    r += __shfl_down(r, 4);
    r += __shfl_down(r, 2);
    r += __shfl_down(r, 1);
    if (h == 0) out[b * SEQ + q] = c0 + r;
}

extern "C" void kernel_launch(void* const* d_in, const int* in_sizes, int n_in,
                              void* d_out, int out_size, void* d_ws, size_t ws_size,
                              hipStream_t stream) {
    const float* x    = (const float*)d_in[0];
    const float* w_in = (const float*)d_in[1];
    const float* b_in = (const float*)d_in[2];
    const float* wq   = (const float*)d_in[3];
    const float* wk   = (const float*)d_in[4];
    const float* wv   = (const float*)d_in[5];
    const float* wo   = (const float*)d_in[6];
    const float* bo   = (const float*)d_in[7];
    const float* wf   = (const float*)d_in[8];
    const float* bf   = (const float*)d_in[9];
    float* out = (float*)d_out;
    float* ws  = (float*)d_ws;

    k1_weights<<<512, 256, 0, stream>>>(x, w_in, b_in, wq, wk, wv, wo, wf, ws);
    k2_eval<<<256, 256, 0, stream>>>(x, bo, wf, bf, ws, out);
}